// Round 6
// baseline (145.539 us; speedup 1.0000x reference)
//
#include <hip/hip_runtime.h>
#include <hip/hip_bf16.h>

#define B_ 4
#define L_ 1024
#define E_ 256
#define S_ 32

typedef __bf16 bf16x8 __attribute__((ext_vector_type(8)));
typedef float f32x4 __attribute__((ext_vector_type(4)));

__device__ __forceinline__ __bf16 bf_from_bits(unsigned short u) {
    __bf16 b;
    __builtin_memcpy(&b, &u, 2);
    return b;
}

// fp32 -> bf16 hi (truncate) + bf16 lo (residual, RTNE).
__device__ __forceinline__ void split1(float x, unsigned short& h, unsigned short& l) {
    const unsigned u  = __float_as_uint(x);
    const unsigned hb = u & 0xFFFF0000u;
    h = (unsigned short)(hb >> 16);
    __bf16 lo = (__bf16)(x - __uint_as_float(hb));
    unsigned short lu;
    __builtin_memcpy(&lu, &lo, 2);
    l = lu;
}

// Path-B fallback only.
__device__ __forceinline__ void load8split(const float* __restrict__ p,
                                           bf16x8& h, bf16x8& l) {
    const float4 x0 = *(const float4*)p;
    const float4 x1 = *(const float4*)(p + 4);
    const float xs[8] = {x0.x, x0.y, x0.z, x0.w, x1.x, x1.y, x1.z, x1.w};
#pragma unroll
    for (int j = 0; j < 8; ++j) {
        const unsigned hb = __float_as_uint(xs[j]) & 0xFFFF0000u;
        h[j] = bf_from_bits((unsigned short)(__float_as_uint(xs[j]) >> 16));
        l[j] = (__bf16)(xs[j] - __uint_as_float(hb));
    }
}

// ===========================================================================
// Kernel 0: presplit — fp32 q (4096x256) and Wq/Wk/Wv (256x256 each) into
// bf16 hi/lo arrays so the fused kernel does zero conversion VALU work.
// 608 blocks x 256 thr x 8 elems = 1,245,184 = 1048576 (A) + 3*65536 (W).
// ===========================================================================
__global__ __launch_bounds__(256) void presplit(
    const float* __restrict__ A,
    const float* __restrict__ Wq, const float* __restrict__ Wk,
    const float* __restrict__ Wv,
    unsigned short* __restrict__ Ah, unsigned short* __restrict__ Al,
    unsigned short* __restrict__ Wh, unsigned short* __restrict__ Wl)
{
    const int e8 = (blockIdx.x * 256 + threadIdx.x) * 8;
    const float* src;
    unsigned short* dh;
    unsigned short* dl;
    if (e8 < 1048576) {
        src = A + e8; dh = Ah + e8; dl = Al + e8;
    } else {
        const int r = e8 - 1048576;
        const int m = r >> 16;          // 0=Wq 1=Wk 2=Wv (z order)
        const int o = r & 65535;
        src = (m == 0 ? Wq : m == 1 ? Wk : Wv) + o;
        dh = Wh + r; dl = Wl + r;
    }
    const float4 x0 = *(const float4*)src;
    const float4 x1 = *(const float4*)(src + 4);
    const float xs[8] = {x0.x, x0.y, x0.z, x0.w, x1.x, x1.y, x1.z, x1.w};
    unsigned short hs[8], ls[8];
#pragma unroll
    for (int j = 0; j < 8; ++j) split1(xs[j], hs[j], ls[j]);
    *(ushort4*)(dh)     = make_ushort4(hs[0], hs[1], hs[2], hs[3]);
    *(ushort4*)(dh + 4) = make_ushort4(hs[4], hs[5], hs[6], hs[7]);
    *(ushort4*)(dl)     = make_ushort4(ls[0], ls[1], ls[2], ls[3]);
    *(ushort4*)(dl + 4) = make_ushort4(ls[4], ls[5], ls[6], ls[7]);
}

// ===========================================================================
// Fused kernel: projection (MFMA from presplit bf16) -> LDS -> windowed
// per-channel softmax + context + sigmoid^2.
// Block = (32 i-rows, 64 channels, one batch); grid (32, 4, 4) = 512 blocks.
// Phase 1: wave w owns col-tile ct=w. For each matrix p in {K,V,Q}: hold all
//   16 W hi/lo fragments (64 VGPR) in registers, loop row-tiles (K/V: 6 halo
//   tiles, Q: 2), 24 MFMA per tile (3-term hi/lo product), write C to LDS.
// Phase 2: stage2c scheme — thread = (channel-quad, row-pair); rows share K/V
//   LDS reads; row2's P[w-1] register-carried; w=0/64 edge taps peeled
//   (strict mask -> logit 0 -> e=1); exp2 domain.
// LDS: (96+96+32+65) rows x 68 floats = 78,608 B -> 2 blocks/CU.
// MFMA 16x16x32 bf16 mapping (verified r3): A-op A[m=lane&15][k=(lane>>4)*8+j];
// B-op W[n=lane&15][k]; C/D col(n)=lane&15, row(m)=(lane>>4)*4+reg.
// ===========================================================================
#define PS2 68
#define LOG2E 1.4426950408889634f

__global__ __launch_bounds__(256, 2) void aft_fused2(
    const unsigned short* __restrict__ Ah, const unsigned short* __restrict__ Al,
    const unsigned short* __restrict__ Wh, const unsigned short* __restrict__ Wl,
    const float* __restrict__ bq, const float* __restrict__ bk,
    const float* __restrict__ bv, const float* __restrict__ pb,
    float* __restrict__ out)
{
    __shared__ float Kw[96][PS2];
    __shared__ float Vw[96][PS2];
    __shared__ float Qw[32][PS2];
    __shared__ float Pw[2 * S_ + 1][PS2];

    const int tid = threadIdx.x;
    const int i0 = blockIdx.x * 32;
    const int b  = blockIdx.y;
    const int c0 = blockIdx.z * 64;

    // ---- stage pos_bias slice (independent of phase-1 writes) ----
    for (int idx = tid; idx < (2 * S_ + 1) * 16; idx += 256) {
        const int r  = idx >> 4;
        const int cc = (idx & 15) * 4;
        *(float4*)&Pw[r][cc] = *(const float4*)(pb + (size_t)r * E_ + c0 + cc);
    }

    // ---- Phase 1: projections ----
    const int wave = tid >> 6;
    const int lane = tid & 63;
    const int rsel = lane & 15;
    const int koff = (lane >> 4) * 8;

    const int ct = wave;                       // col-tile 0..3
    const int n  = c0 + ct * 16 + rsel;        // output channel this lane loads W for
    const int colc = ct * 16 + rsel;           // LDS column of C/D
    const int crow = (lane >> 4) * 4;          // C/D row base within tile

#pragma unroll
    for (int p = 0; p < 3; ++p) {              // 0=K 1=V 2=Q
        const int z = (p == 0) ? 1 : (p == 1) ? 2 : 0;   // presplit z: 0=Wq 1=Wk 2=Wv
        const float bias = (p == 0) ? bk[n] : (p == 1) ? bv[n] : bq[n];
        float* dst = (p == 0) ? &Kw[0][0] : (p == 1) ? &Vw[0][0] : &Qw[0][0];
        const int nrt = (p == 2) ? 2 : 6;

        const unsigned short* wh = Wh + (size_t)z * 65536 + (size_t)n * 256 + koff;
        const unsigned short* wl = Wl + (size_t)z * 65536 + (size_t)n * 256 + koff;
        bf16x8 BH[8], BL[8];
#pragma unroll
        for (int s = 0; s < 8; ++s) {
            BH[s] = *(const bf16x8*)(wh + s * 32);
            BL[s] = *(const bf16x8*)(wl + s * 32);
        }

        for (int rt = 0; rt < nrt; ++rt) {
            int arow = (p == 2) ? (i0 + rt * 16 + rsel)
                                : (i0 - S_ + rt * 16 + rsel);
            arow = arow < 0 ? 0 : (arow > L_ - 1 ? L_ - 1 : arow); // masked in ph2
            const size_t abase = ((size_t)b * L_ + arow) * 256 + koff;
            const unsigned short* pah = Ah + abase;
            const unsigned short* pal = Al + abase;

            f32x4 acc = {0.f, 0.f, 0.f, 0.f};
#pragma unroll
            for (int s = 0; s < 8; ++s) {
                const bf16x8 ah = *(const bf16x8*)(pah + s * 32);
                const bf16x8 al = *(const bf16x8*)(pal + s * 32);
                acc = __builtin_amdgcn_mfma_f32_16x16x32_bf16(ah, BH[s], acc, 0, 0, 0);
                acc = __builtin_amdgcn_mfma_f32_16x16x32_bf16(ah, BL[s], acc, 0, 0, 0);
                acc = __builtin_amdgcn_mfma_f32_16x16x32_bf16(al, BH[s], acc, 0, 0, 0);
            }

            const int row0 = rt * 16 + crow;
#pragma unroll
            for (int r = 0; r < 4; ++r)
                dst[(size_t)(row0 + r) * PS2 + colc] = acc[r] + bias;
        }
    }
    __syncthreads();

    // ---- Phase 2: windowed softmax from LDS ----
    const int cq = (tid & 15) * 4;     // channel quad
    const int t  = tid >> 4;           // row-pair 0..15
    const int i1 = i0 + 2 * t;
    const int i2 = i1 + 1;
    const int r0 = 2 * t;              // LDS halo row of j = i1 - S

    const float4 qa  = *(const float4*)&Qw[2 * t][cq];
    const float4 qb2 = *(const float4*)&Qw[2 * t + 1][cq];
    const float4 q2a = make_float4(qa.x * LOG2E, qa.y * LOG2E, qa.z * LOG2E, qa.w * LOG2E);
    const float4 q2b = make_float4(qb2.x * LOG2E, qb2.y * LOG2E, qb2.z * LOG2E, qb2.w * LOG2E);

    float4 den1 = {0, 0, 0, 0}, num1 = {0, 0, 0, 0};
    float4 den2 = {0, 0, 0, 0}, num2 = {0, 0, 0, 0};

    const bool interior = (blockIdx.x >= 1) && (blockIdx.x <= (L_ / 32) - 2);

    if (interior) {
        {   // w1 = 0: row1 edge tap (e=1); row2 w=-1 out of window
            const float4 v = *(const float4*)&Vw[r0][cq];
            den1.x += 1.f; den1.y += 1.f; den1.z += 1.f; den1.w += 1.f;
            num1.x += v.x; num1.y += v.y; num1.z += v.z; num1.w += v.w;
        }
        float4 p_old;
        {   // w1 = 1: row1 normal; row2 edge tap
            const float4 p = *(const float4*)&Pw[1][cq];
            const float4 k = *(const float4*)&Kw[r0 + 1][cq];
            const float4 v = *(const float4*)&Vw[r0 + 1][cq];
            const float e0 = __builtin_amdgcn_exp2f(q2a.x * (k.x + p.x));
            const float e1 = __builtin_amdgcn_exp2f(q2a.y * (k.y + p.y));
            const float e2 = __builtin_amdgcn_exp2f(q2a.z * (k.z + p.z));
            const float e3 = __builtin_amdgcn_exp2f(q2a.w * (k.w + p.w));
            den1.x += e0; den1.y += e1; den1.z += e2; den1.w += e3;
            num1.x += e0 * v.x; num1.y += e1 * v.y; num1.z += e2 * v.z; num1.w += e3 * v.w;
            den2.x += 1.f; den2.y += 1.f; den2.z += 1.f; den2.w += 1.f;
            num2.x += v.x; num2.y += v.y; num2.z += v.z; num2.w += v.w;
            p_old = p;
        }
        for (int w1 = 2; w1 <= 63; ++w1) {
            const float4 p = *(const float4*)&Pw[w1][cq];
            const float4 k = *(const float4*)&Kw[r0 + w1][cq];
            const float4 v = *(const float4*)&Vw[r0 + w1][cq];
            const float a0 = __builtin_amdgcn_exp2f(q2a.x * (k.x + p.x));
            const float a1 = __builtin_amdgcn_exp2f(q2a.y * (k.y + p.y));
            const float a2 = __builtin_amdgcn_exp2f(q2a.z * (k.z + p.z));
            const float a3 = __builtin_amdgcn_exp2f(q2a.w * (k.w + p.w));
            const float b0 = __builtin_amdgcn_exp2f(q2b.x * (k.x + p_old.x));
            const float b1 = __builtin_amdgcn_exp2f(q2b.y * (k.y + p_old.y));
            const float b2 = __builtin_amdgcn_exp2f(q2b.z * (k.z + p_old.z));
            const float b3 = __builtin_amdgcn_exp2f(q2b.w * (k.w + p_old.w));
            den1.x += a0; den1.y += a1; den1.z += a2; den1.w += a3;
            num1.x += a0 * v.x; num1.y += a1 * v.y; num1.z += a2 * v.z; num1.w += a3 * v.w;
            den2.x += b0; den2.y += b1; den2.z += b2; den2.w += b3;
            num2.x += b0 * v.x; num2.y += b1 * v.y; num2.z += b2 * v.z; num2.w += b3 * v.w;
            p_old = p;
        }
        {   // w1 = 64: row1 edge; row2 normal with p_old = P[63]
            const float4 k = *(const float4*)&Kw[r0 + 64][cq];
            const float4 v = *(const float4*)&Vw[r0 + 64][cq];
            den1.x += 1.f; den1.y += 1.f; den1.z += 1.f; den1.w += 1.f;
            num1.x += v.x; num1.y += v.y; num1.z += v.z; num1.w += v.w;
            const float b0 = __builtin_amdgcn_exp2f(q2b.x * (k.x + p_old.x));
            const float b1 = __builtin_amdgcn_exp2f(q2b.y * (k.y + p_old.y));
            const float b2 = __builtin_amdgcn_exp2f(q2b.z * (k.z + p_old.z));
            const float b3 = __builtin_amdgcn_exp2f(q2b.w * (k.w + p_old.w));
            den2.x += b0; den2.y += b1; den2.z += b2; den2.w += b3;
            num2.x += b0 * v.x; num2.y += b1 * v.y; num2.z += b2 * v.z; num2.w += b3 * v.w;
        }
        {   // w1 = 65: row2 edge tap
            const float4 v = *(const float4*)&Vw[r0 + 65][cq];
            den2.x += 1.f; den2.y += 1.f; den2.z += 1.f; den2.w += 1.f;
            num2.x += v.x; num2.y += v.y; num2.z += v.z; num2.w += v.w;
        }
    } else {
        // guarded path for the 2 edge i-tiles
#pragma unroll
        for (int rowsel = 0; rowsel < 2; ++rowsel) {
            const int i = rowsel ? i2 : i1;
            const float4 q2 = rowsel ? q2b : q2a;
            float4* den = rowsel ? &den2 : &den1;
            float4* num = rowsel ? &num2 : &num1;
            for (int w = 0; w <= 64; ++w) {
                const int j = i - S_ + w;
                const bool valid = (unsigned)j < (unsigned)L_;
                const int r = (i - i0) + w;          // in [0,95]
                const float4 k = *(const float4*)&Kw[r][cq];
                const float4 v = *(const float4*)&Vw[r][cq];
                const float4 p = *(const float4*)&Pw[w][cq];
                const bool edge = (w == 0) || (w == 64);
                const float lx = edge ? 0.f : q2.x * (k.x + p.x);
                const float ly = edge ? 0.f : q2.y * (k.y + p.y);
                const float lz = edge ? 0.f : q2.z * (k.z + p.z);
                const float lw = edge ? 0.f : q2.w * (k.w + p.w);
                const float e0 = valid ? __builtin_amdgcn_exp2f(lx) : 0.f;
                const float e1 = valid ? __builtin_amdgcn_exp2f(ly) : 0.f;
                const float e2 = valid ? __builtin_amdgcn_exp2f(lz) : 0.f;
                const float e3 = valid ? __builtin_amdgcn_exp2f(lw) : 0.f;
                den->x += e0; den->y += e1; den->z += e2; den->w += e3;
                num->x += e0 * v.x; num->y += e1 * v.y;
                num->z += e2 * v.z; num->w += e3 * v.w;
            }
        }
    }

    // epilogue: sigmoid^2 * ctx   (exp(-q) = exp2(-q2))
    {
        const float s0 = 1.f / (1.f + __builtin_amdgcn_exp2f(-q2a.x));
        const float s1 = 1.f / (1.f + __builtin_amdgcn_exp2f(-q2a.y));
        const float s2 = 1.f / (1.f + __builtin_amdgcn_exp2f(-q2a.z));
        const float s3 = 1.f / (1.f + __builtin_amdgcn_exp2f(-q2a.w));
        float4 o;
        o.x = s0 * s0 * num1.x / den1.x;
        o.y = s1 * s1 * num1.y / den1.y;
        o.z = s2 * s2 * num1.z / den1.z;
        o.w = s3 * s3 * num1.w / den1.w;
        *(float4*)(out + ((size_t)b * L_ + i1) * E_ + c0 + cq) = o;
    }
    {
        const float s0 = 1.f / (1.f + __builtin_amdgcn_exp2f(-q2b.x));
        const float s1 = 1.f / (1.f + __builtin_amdgcn_exp2f(-q2b.y));
        const float s2 = 1.f / (1.f + __builtin_amdgcn_exp2f(-q2b.z));
        const float s3 = 1.f / (1.f + __builtin_amdgcn_exp2f(-q2b.w));
        float4 o;
        o.x = s0 * s0 * num2.x / den2.x;
        o.y = s1 * s1 * num2.y / den2.y;
        o.z = s2 * s2 * num2.z / den2.z;
        o.w = s3 * s3 * num2.w / den2.w;
        *(float4*)(out + ((size_t)b * L_ + i2) * E_ + c0 + cq) = o;
    }
}

// ===========================================================================
// PATH B (ws too small; fallback only): fused fp32 in-register split (r3).
// ===========================================================================
#define TI 32
#define CG 64
#define RK 96
#define LDP 68

__global__ __launch_bounds__(256) void aft_fused(
    const float* __restrict__ q,
    const float* __restrict__ Wq, const float* __restrict__ bq,
    const float* __restrict__ Wk, const float* __restrict__ bk,
    const float* __restrict__ Wv, const float* __restrict__ bv,
    const float* __restrict__ pb,
    float* __restrict__ out)
{
    __shared__ float Kl[RK][LDP];
    __shared__ float Vl[RK][LDP];
    __shared__ float Ql[TI][LDP];

    const int i0 = blockIdx.x * TI;
    const int b  = blockIdx.y;
    const int c0 = blockIdx.z * CG;

    const int wave = threadIdx.x >> 6;
    const int lane = threadIdx.x & 63;
    const int rsel = lane & 15;
    const int koff = (lane >> 4) * 8;

    const float* qb = q + (size_t)b * L_ * E_;

    for (int job = wave; job < 56; job += 4) {
        int p, rt, ct;
        if (job < 24)      { p = 0; rt = job >> 2;        ct = job & 3; }
        else if (job < 48) { p = 1; rt = (job - 24) >> 2; ct = (job - 24) & 3; }
        else               { p = 2; rt = (job - 48) >> 2; ct = (job - 48) & 3; }

        int jrow = (p == 2) ? (i0 + rt * 16 + rsel)
                            : (i0 - S_ + rt * 16 + rsel);
        int jc = jrow < 0 ? 0 : (jrow > L_ - 1 ? L_ - 1 : jrow);
        const float* pa = qb + (size_t)jc * E_ + koff;

        const float* Wm = (p == 0) ? Wk : (p == 1) ? Wv : Wq;
        const float* bm = (p == 0) ? bk : (p == 1) ? bv : bq;
        const int n = c0 + ct * 16 + rsel;
        const float* pw = Wm + (size_t)n * E_ + koff;

        f32x4 acc = {0.f, 0.f, 0.f, 0.f};
#pragma unroll
        for (int k0 = 0; k0 < 256; k0 += 32) {
            bf16x8 ah, al, bh, bl;
            load8split(pa + k0, ah, al);
            load8split(pw + k0, bh, bl);
            acc = __builtin_amdgcn_mfma_f32_16x16x32_bf16(ah, bh, acc, 0, 0, 0);
            acc = __builtin_amdgcn_mfma_f32_16x16x32_bf16(ah, bl, acc, 0, 0, 0);
            acc = __builtin_amdgcn_mfma_f32_16x16x32_bf16(al, bh, acc, 0, 0, 0);
        }

        const float bias = bm[n];
        const int row0 = rt * 16 + (lane >> 4) * 4;
        const int colc = ct * 16 + rsel;
        float* dst = (p == 0) ? &Kl[0][0] : (p == 1) ? &Vl[0][0] : &Ql[0][0];
#pragma unroll
        for (int r = 0; r < 4; ++r)
            dst[(size_t)(row0 + r) * LDP + colc] = acc[r] + bias;
    }
    __syncthreads();

    const int cq  = threadIdx.x & 15;
    const int is0 = threadIdx.x >> 4;
    const int cL  = cq * 4;
    const int cG  = c0 + cL;
    const float* pbc = pb + cG;

    for (int rr = is0; rr < TI; rr += 16) {
        const int i = i0 + rr;
        const float4 qv = *(const float4*)&Ql[rr][cL];

        float den0 = 0.f, den1 = 0.f, den2 = 0.f, den3 = 0.f;
        float num0 = 0.f, num1 = 0.f, num2 = 0.f, num3 = 0.f;

        const int jlo = (i - S_ < 0) ? 0 : (i - S_);
        const int jhi = (i + S_ > L_ - 1) ? (L_ - 1) : (i + S_);

        for (int j = jlo; j <= jhi; ++j) {
            const int r = j - (i0 - S_);
            const int w = j - i + S_;
            const float4 vv = *(const float4*)&Vl[r][cL];

            float kx = 0.f, ky = 0.f, kz = 0.f, kw = 0.f;
            if (w != 0 && w != 2 * S_) {
                const float4 kk = *(const float4*)&Kl[r][cL];
                const float4 pp = *(const float4*)(pbc + (size_t)w * E_);
                kx = kk.x + pp.x;
                ky = kk.y + pp.y;
                kz = kk.z + pp.z;
                kw = kk.w + pp.w;
            }
            const float e0 = __expf(qv.x * kx);
            const float e1 = __expf(qv.y * ky);
            const float e2 = __expf(qv.z * kz);
            const float e3 = __expf(qv.w * kw);
            den0 += e0; den1 += e1; den2 += e2; den3 += e3;
            num0 += e0 * vv.x; num1 += e1 * vv.y;
            num2 += e2 * vv.z; num3 += e3 * vv.w;
        }

        const float s0 = 1.f / (1.f + __expf(-qv.x));
        const float s1 = 1.f / (1.f + __expf(-qv.y));
        const float s2 = 1.f / (1.f + __expf(-qv.z));
        const float s3 = 1.f / (1.f + __expf(-qv.w));

        float4 o;
        o.x = s0 * s0 * num0 / den0;
        o.y = s1 * s1 * num1 / den1;
        o.z = s2 * s2 * num2 / den2;
        o.w = s3 * s3 * num3 / den3;
        *(float4*)(out + ((size_t)b * L_ + i) * E_ + cG) = o;
    }
}

extern "C" void kernel_launch(void* const* d_in, const int* in_sizes, int n_in,
                              void* d_out, int out_size, void* d_ws, size_t ws_size,
                              hipStream_t stream) {
    const float* q  = (const float*)d_in[0];
    const float* Wq = (const float*)d_in[1];
    const float* bq = (const float*)d_in[2];
    const float* Wk = (const float*)d_in[3];
    const float* bk = (const float*)d_in[4];
    const float* Wv = (const float*)d_in[5];
    const float* bv = (const float*)d_in[6];
    const float* pb = (const float*)d_in[7];

    // ws layout: Ah/Al bf16 (4 MB) + Wh/Wl bf16 (768 KB)  ~= 5 MB
    const size_t needA = ((size_t)2 * 1048576 + (size_t)2 * 196608) * 2;

    if (ws_size >= needA) {
        unsigned short* Ah = (unsigned short*)d_ws;
        unsigned short* Al = Ah + 1048576;
        unsigned short* Wh = Al + 1048576;
        unsigned short* Wl = Wh + 196608;

        presplit<<<dim3(608), 256, 0, stream>>>(q, Wq, Wk, Wv, Ah, Al, Wh, Wl);
        aft_fused2<<<dim3(L_ / 32, B_, E_ / 64), 256, 0, stream>>>(
            Ah, Al, Wh, Wl, bq, bk, bv, pb, (float*)d_out);
    } else {
        aft_fused<<<dim3(L_ / TI, B_, E_ / CG), 256, 0, stream>>>(
            q, Wq, bq, Wk, bk, Wv, bv, pb, (float*)d_out);
    }
}

// Round 7
// 126.547 us; speedup vs baseline: 1.1501x; 1.1501x over previous
//
#include <hip/hip_runtime.h>
#include <hip/hip_bf16.h>

#define B_ 4
#define L_ 1024
#define E_ 256
#define S_ 32
#define LOG2E 1.4426950408889634f

typedef __bf16 bf16x8 __attribute__((ext_vector_type(8)));
typedef float f32x4 __attribute__((ext_vector_type(4)));

__device__ __forceinline__ __bf16 bf_from_bits(unsigned short u) {
    __bf16 b;
    __builtin_memcpy(&b, &u, 2);
    return b;
}

// fp32 -> bf16 hi (truncate) + bf16 lo (residual, RTNE).
__device__ __forceinline__ void split1(float x, unsigned short& h, unsigned short& l) {
    const unsigned u  = __float_as_uint(x);
    const unsigned hb = u & 0xFFFF0000u;
    h = (unsigned short)(hb >> 16);
    __bf16 lo = (__bf16)(x - __uint_as_float(hb));
    unsigned short lu;
    __builtin_memcpy(&lu, &lo, 2);
    l = lu;
}

// Path-B fallback only.
__device__ __forceinline__ void load8split(const float* __restrict__ p,
                                           bf16x8& h, bf16x8& l) {
    const float4 x0 = *(const float4*)p;
    const float4 x1 = *(const float4*)(p + 4);
    const float xs[8] = {x0.x, x0.y, x0.z, x0.w, x1.x, x1.y, x1.z, x1.w};
#pragma unroll
    for (int j = 0; j < 8; ++j) {
        const unsigned hb = __float_as_uint(xs[j]) & 0xFFFF0000u;
        h[j] = bf_from_bits((unsigned short)(__float_as_uint(xs[j]) >> 16));
        l[j] = (__bf16)(xs[j] - __uint_as_float(hb));
    }
}

// ===========================================================================
// Kernel 0: presplit — fp32 q (4096x256) and Wq/Wk/Wv (256x256 each) into
// bf16 hi/lo arrays (zero conversion VALU in the GEMM).
// ===========================================================================
__global__ __launch_bounds__(256) void presplit(
    const float* __restrict__ A,
    const float* __restrict__ Wq, const float* __restrict__ Wk,
    const float* __restrict__ Wv,
    unsigned short* __restrict__ Ah, unsigned short* __restrict__ Al,
    unsigned short* __restrict__ Wh, unsigned short* __restrict__ Wl)
{
    const int e8 = (blockIdx.x * 256 + threadIdx.x) * 8;
    const float* src;
    unsigned short* dh;
    unsigned short* dl;
    if (e8 < 1048576) {
        src = A + e8; dh = Ah + e8; dl = Al + e8;
    } else {
        const int r = e8 - 1048576;
        const int m = r >> 16;          // 0=Wq 1=Wk 2=Wv
        const int o = r & 65535;
        src = (m == 0 ? Wq : m == 1 ? Wk : Wv) + o;
        dh = Wh + r; dl = Wl + r;
    }
    const float4 x0 = *(const float4*)src;
    const float4 x1 = *(const float4*)(src + 4);
    const float xs[8] = {x0.x, x0.y, x0.z, x0.w, x1.x, x1.y, x1.z, x1.w};
    unsigned short hs[8], ls[8];
#pragma unroll
    for (int j = 0; j < 8; ++j) split1(xs[j], hs[j], ls[j]);
    *(ushort4*)(dh)     = make_ushort4(hs[0], hs[1], hs[2], hs[3]);
    *(ushort4*)(dh + 4) = make_ushort4(hs[4], hs[5], hs[6], hs[7]);
    *(ushort4*)(dl)     = make_ushort4(ls[0], ls[1], ls[2], ls[3]);
    *(ushort4*)(dl + 4) = make_ushort4(ls[4], ls[5], ls[6], ls[7]);
}

// ===========================================================================
// Kernel 1: Q/K/V projection GEMM. out = A*W^T + b, fp32 out to workspace.
// Grid (128, 2, 3) = 768 blocks (3/CU). Wave = 2 M-tiles x 2 N-tiles:
// per K-step 8 x 16B loads + 12 MFMA (3-term hi/lo product).
// MFMA 16x16x32 bf16 mapping (verified r3): A-op A[m=lane&15][k=(lane>>4)*8+j];
// B-op W[n=lane&15][k]; C/D col(n)=lane&15, row(m)=(lane>>4)*4+reg.
// ===========================================================================
__global__ __launch_bounds__(256) void qkv_gemm4(
    const unsigned short* __restrict__ Ah, const unsigned short* __restrict__ Al,
    const unsigned short* __restrict__ Wh, const unsigned short* __restrict__ Wl,
    const float* __restrict__ bq, const float* __restrict__ bk,
    const float* __restrict__ bv,
    float* __restrict__ Qo, float* __restrict__ Ko, float* __restrict__ Vo)
{
    const int z = blockIdx.z;
    const float* bm = (z == 0) ? bq : (z == 1) ? bk : bv;
    float* Om       = (z == 0) ? Qo : (z == 1) ? Ko : Vo;
    const unsigned short* Whz = Wh + (size_t)z * 65536;
    const unsigned short* Wlz = Wl + (size_t)z * 65536;

    const int wave = threadIdx.x >> 6;
    const int lane = threadIdx.x & 63;
    const int rsel = lane & 15;
    const int koff = (lane >> 4) * 8;

    const int m0 = blockIdx.x * 32;
    const int nb = blockIdx.y * 128 + wave * 32;

    const unsigned short* pa0h = Ah + (size_t)(m0 + rsel) * 256 + koff;
    const unsigned short* pa0l = Al + (size_t)(m0 + rsel) * 256 + koff;
    const unsigned short* pa1h = pa0h + 16 * 256;
    const unsigned short* pa1l = pa0l + 16 * 256;
    const unsigned short* pw0h = Whz + (size_t)(nb + rsel) * 256 + koff;
    const unsigned short* pw0l = Wlz + (size_t)(nb + rsel) * 256 + koff;
    const unsigned short* pw1h = pw0h + 16 * 256;
    const unsigned short* pw1l = pw0l + 16 * 256;

    f32x4 acc[2][2];
#pragma unroll
    for (int mt = 0; mt < 2; ++mt)
#pragma unroll
        for (int nt = 0; nt < 2; ++nt)
            acc[mt][nt] = (f32x4){0.f, 0.f, 0.f, 0.f};

#pragma unroll
    for (int k0 = 0; k0 < 256; k0 += 32) {
        bf16x8 ah[2], al[2], bh[2], bl[2];
        ah[0] = *(const bf16x8*)(pa0h + k0);
        al[0] = *(const bf16x8*)(pa0l + k0);
        ah[1] = *(const bf16x8*)(pa1h + k0);
        al[1] = *(const bf16x8*)(pa1l + k0);
        bh[0] = *(const bf16x8*)(pw0h + k0);
        bl[0] = *(const bf16x8*)(pw0l + k0);
        bh[1] = *(const bf16x8*)(pw1h + k0);
        bl[1] = *(const bf16x8*)(pw1l + k0);
#pragma unroll
        for (int mt = 0; mt < 2; ++mt)
#pragma unroll
            for (int nt = 0; nt < 2; ++nt) {
                acc[mt][nt] = __builtin_amdgcn_mfma_f32_16x16x32_bf16(
                    ah[mt], bh[nt], acc[mt][nt], 0, 0, 0);
                acc[mt][nt] = __builtin_amdgcn_mfma_f32_16x16x32_bf16(
                    ah[mt], bl[nt], acc[mt][nt], 0, 0, 0);
                acc[mt][nt] = __builtin_amdgcn_mfma_f32_16x16x32_bf16(
                    al[mt], bh[nt], acc[mt][nt], 0, 0, 0);
            }
    }

#pragma unroll
    for (int mt = 0; mt < 2; ++mt) {
        const int mrow = m0 + mt * 16 + (lane >> 4) * 4;
#pragma unroll
        for (int nt = 0; nt < 2; ++nt) {
            const int n = nb + nt * 16 + rsel;
            const float bias = bm[n];
#pragma unroll
            for (int r = 0; r < 4; ++r)
                Om[(size_t)(mrow + r) * 256 + n] = acc[mt][nt][r] + bias;
        }
    }
}

// ===========================================================================
// Kernel 2: windowed per-channel softmax + context + sigmoid^2.
// High-occupancy redesign: block = 32 i-rows x 32 channels, one batch;
// grid (32, 4, 8) = 1024 blocks. ONLY pos_bias in LDS (9.4 KB, stride 36 =
// 144 B keeps float4 alignment and rotates banks; reads are same-row
// broadcast -> conflict-free). K/V float4 from global: per-block working
// set 96 rows x 128 B x 2 = 24 KB -> L1-resident. Interior loop is a
// FIXED 63-trip branch-free loop, #pragma unroll 7 -> ~14 loads in flight
// hides L2 latency (rounds 4-6 were latency-bound at 2 waves/SIMD).
// Edge taps w=0/64 peeled (strict mask -> logit 0 -> e=1). exp2 domain.
// ===========================================================================
#define SPS 36

__global__ __launch_bounds__(256, 4) void aft_stage3(
    const float* __restrict__ Q, const float* __restrict__ K,
    const float* __restrict__ V, const float* __restrict__ pb,
    float* __restrict__ out)
{
    __shared__ float Pw[2 * S_ + 1][SPS];

    const int tid = threadIdx.x;
    const int i0 = blockIdx.x * 32;
    const int b  = blockIdx.y;
    const int c0 = blockIdx.z * 32;

    // stage pos_bias slice: 65 rows x 8 quads
    for (int idx = tid; idx < 65 * 8; idx += 256) {
        const int r = idx >> 3;
        const int q = (idx & 7) * 4;
        *(float4*)&Pw[r][q] = *(const float4*)(pb + (size_t)r * E_ + c0 + q);
    }
    __syncthreads();

    const int c4 = (tid & 7) * 4;      // channel quad within 32-ch slice
    const int ro = tid >> 3;           // row 0..31
    const int i  = i0 + ro;

    const float4 qv = *(const float4*)(Q + ((size_t)b * L_ + i) * E_ + c0 + c4);
    const float q2x = qv.x * LOG2E, q2y = qv.y * LOG2E;
    const float q2z = qv.z * LOG2E, q2w = qv.w * LOG2E;

    float den0 = 0.f, den1 = 0.f, den2 = 0.f, den3 = 0.f;
    float num0 = 0.f, num1 = 0.f, num2 = 0.f, num3 = 0.f;

    const float* kp = K + ((size_t)b * L_ + (i - S_)) * E_ + c0 + c4;
    const float* vp = V + ((size_t)b * L_ + (i - S_)) * E_ + c0 + c4;

    const bool interior = (blockIdx.x >= 1) && (blockIdx.x <= 30);

    if (interior) {
        {   // w = 0: edge tap, e = 1
            const float4 v = *(const float4*)vp;
            den0 += 1.f; den1 += 1.f; den2 += 1.f; den3 += 1.f;
            num0 += v.x; num1 += v.y; num2 += v.z; num3 += v.w;
        }
#pragma unroll 7
        for (int w = 1; w <= 63; ++w) {
            const float4 kk = *(const float4*)(kp + (size_t)w * E_);
            const float4 vv = *(const float4*)(vp + (size_t)w * E_);
            const float4 pp = *(const float4*)&Pw[w][c4];
            const float e0 = __builtin_amdgcn_exp2f(q2x * (kk.x + pp.x));
            const float e1 = __builtin_amdgcn_exp2f(q2y * (kk.y + pp.y));
            const float e2 = __builtin_amdgcn_exp2f(q2z * (kk.z + pp.z));
            const float e3 = __builtin_amdgcn_exp2f(q2w * (kk.w + pp.w));
            den0 += e0; den1 += e1; den2 += e2; den3 += e3;
            num0 += e0 * vv.x; num1 += e1 * vv.y;
            num2 += e2 * vv.z; num3 += e3 * vv.w;
        }
        {   // w = 64: edge tap, e = 1
            const float4 v = *(const float4*)(vp + (size_t)64 * E_);
            den0 += 1.f; den1 += 1.f; den2 += 1.f; den3 += 1.f;
            num0 += v.x; num1 += v.y; num2 += v.z; num3 += v.w;
        }
    } else {
        const float* KbB = K + (size_t)b * L_ * E_ + c0 + c4;
        const float* VbB = V + (size_t)b * L_ * E_ + c0 + c4;
        for (int w = 0; w <= 64; ++w) {
            const int j = i - S_ + w;
            const bool valid = (unsigned)j < (unsigned)L_;
            const int jc = j < 0 ? 0 : (j > L_ - 1 ? L_ - 1 : j);
            const float4 kk = *(const float4*)(KbB + (size_t)jc * E_);
            const float4 vv = *(const float4*)(VbB + (size_t)jc * E_);
            const float4 pp = *(const float4*)&Pw[w][c4];
            const bool edge = (w == 0) || (w == 64);
            const float lx = edge ? 0.f : q2x * (kk.x + pp.x);
            const float ly = edge ? 0.f : q2y * (kk.y + pp.y);
            const float lz = edge ? 0.f : q2z * (kk.z + pp.z);
            const float lw = edge ? 0.f : q2w * (kk.w + pp.w);
            const float e0 = valid ? __builtin_amdgcn_exp2f(lx) : 0.f;
            const float e1 = valid ? __builtin_amdgcn_exp2f(ly) : 0.f;
            const float e2 = valid ? __builtin_amdgcn_exp2f(lz) : 0.f;
            const float e3 = valid ? __builtin_amdgcn_exp2f(lw) : 0.f;
            den0 += e0; den1 += e1; den2 += e2; den3 += e3;
            num0 += e0 * vv.x; num1 += e1 * vv.y;
            num2 += e2 * vv.z; num3 += e3 * vv.w;
        }
    }

    // sigmoid^2 * ctx   (exp(-q) = exp2(-q2))
    const float s0 = 1.f / (1.f + __builtin_amdgcn_exp2f(-q2x));
    const float s1 = 1.f / (1.f + __builtin_amdgcn_exp2f(-q2y));
    const float s2 = 1.f / (1.f + __builtin_amdgcn_exp2f(-q2z));
    const float s3 = 1.f / (1.f + __builtin_amdgcn_exp2f(-q2w));
    float4 o;
    o.x = s0 * s0 * num0 / den0;
    o.y = s1 * s1 * num1 / den1;
    o.z = s2 * s2 * num2 / den2;
    o.w = s3 * s3 * num3 / den3;
    *(float4*)(out + ((size_t)b * L_ + i) * E_ + c0 + c4) = o;
}

// ===========================================================================
// PATH B (ws too small; fallback only): fused fp32 in-register split (r3).
// ===========================================================================
#define TI 32
#define CG 64
#define RK 96
#define LDP 68

__global__ __launch_bounds__(256) void aft_fused(
    const float* __restrict__ q,
    const float* __restrict__ Wq, const float* __restrict__ bq,
    const float* __restrict__ Wk, const float* __restrict__ bk,
    const float* __restrict__ Wv, const float* __restrict__ bv,
    const float* __restrict__ pb,
    float* __restrict__ out)
{
    __shared__ float Kl[RK][LDP];
    __shared__ float Vl[RK][LDP];
    __shared__ float Ql[TI][LDP];

    const int i0 = blockIdx.x * TI;
    const int b  = blockIdx.y;
    const int c0 = blockIdx.z * CG;

    const int wave = threadIdx.x >> 6;
    const int lane = threadIdx.x & 63;
    const int rsel = lane & 15;
    const int koff = (lane >> 4) * 8;

    const float* qb = q + (size_t)b * L_ * E_;

    for (int job = wave; job < 56; job += 4) {
        int p, rt, ct;
        if (job < 24)      { p = 0; rt = job >> 2;        ct = job & 3; }
        else if (job < 48) { p = 1; rt = (job - 24) >> 2; ct = (job - 24) & 3; }
        else               { p = 2; rt = (job - 48) >> 2; ct = (job - 48) & 3; }

        int jrow = (p == 2) ? (i0 + rt * 16 + rsel)
                            : (i0 - S_ + rt * 16 + rsel);
        int jc = jrow < 0 ? 0 : (jrow > L_ - 1 ? L_ - 1 : jrow);
        const float* pa = qb + (size_t)jc * E_ + koff;

        const float* Wm = (p == 0) ? Wk : (p == 1) ? Wv : Wq;
        const float* bm = (p == 0) ? bk : (p == 1) ? bv : bq;
        const int n = c0 + ct * 16 + rsel;
        const float* pw = Wm + (size_t)n * E_ + koff;

        f32x4 acc = {0.f, 0.f, 0.f, 0.f};
#pragma unroll
        for (int k0 = 0; k0 < 256; k0 += 32) {
            bf16x8 ah, al, bh, bl;
            load8split(pa + k0, ah, al);
            load8split(pw + k0, bh, bl);
            acc = __builtin_amdgcn_mfma_f32_16x16x32_bf16(ah, bh, acc, 0, 0, 0);
            acc = __builtin_amdgcn_mfma_f32_16x16x32_bf16(ah, bl, acc, 0, 0, 0);
            acc = __builtin_amdgcn_mfma_f32_16x16x32_bf16(al, bh, acc, 0, 0, 0);
        }

        const float bias = bm[n];
        const int row0 = rt * 16 + (lane >> 4) * 4;
        const int colc = ct * 16 + rsel;
        float* dst = (p == 0) ? &Kl[0][0] : (p == 1) ? &Vl[0][0] : &Ql[0][0];
#pragma unroll
        for (int r = 0; r < 4; ++r)
            dst[(size_t)(row0 + r) * LDP + colc] = acc[r] + bias;
    }
    __syncthreads();

    const int cq  = threadIdx.x & 15;
    const int is0 = threadIdx.x >> 4;
    const int cL  = cq * 4;
    const int cG  = c0 + cL;
    const float* pbc = pb + cG;

    for (int rr = is0; rr < TI; rr += 16) {
        const int i = i0 + rr;
        const float4 qv = *(const float4*)&Ql[rr][cL];

        float den0 = 0.f, den1 = 0.f, den2 = 0.f, den3 = 0.f;
        float num0 = 0.f, num1 = 0.f, num2 = 0.f, num3 = 0.f;

        const int jlo = (i - S_ < 0) ? 0 : (i - S_);
        const int jhi = (i + S_ > L_ - 1) ? (L_ - 1) : (i + S_);

        for (int j = jlo; j <= jhi; ++j) {
            const int r = j - (i0 - S_);
            const int w = j - i + S_;
            const float4 vv = *(const float4*)&Vl[r][cL];

            float kx = 0.f, ky = 0.f, kz = 0.f, kw = 0.f;
            if (w != 0 && w != 2 * S_) {
                const float4 kk = *(const float4*)&Kl[r][cL];
                const float4 pp = *(const float4*)(pbc + (size_t)w * E_);
                kx = kk.x + pp.x;
                ky = kk.y + pp.y;
                kz = kk.z + pp.z;
                kw = kk.w + pp.w;
            }
            const float e0 = __expf(qv.x * kx);
            const float e1 = __expf(qv.y * ky);
            const float e2 = __expf(qv.z * kz);
            const float e3 = __expf(qv.w * kw);
            den0 += e0; den1 += e1; den2 += e2; den3 += e3;
            num0 += e0 * vv.x; num1 += e1 * vv.y;
            num2 += e2 * vv.z; num3 += e3 * vv.w;
        }

        const float s0 = 1.f / (1.f + __expf(-qv.x));
        const float s1 = 1.f / (1.f + __expf(-qv.y));
        const float s2 = 1.f / (1.f + __expf(-qv.z));
        const float s3 = 1.f / (1.f + __expf(-qv.w));

        float4 o;
        o.x = s0 * s0 * num0 / den0;
        o.y = s1 * s1 * num1 / den1;
        o.z = s2 * s2 * num2 / den2;
        o.w = s3 * s3 * num3 / den3;
        *(float4*)(out + ((size_t)b * L_ + i) * E_ + cG) = o;
    }
}

extern "C" void kernel_launch(void* const* d_in, const int* in_sizes, int n_in,
                              void* d_out, int out_size, void* d_ws, size_t ws_size,
                              hipStream_t stream) {
    const float* q  = (const float*)d_in[0];
    const float* Wq = (const float*)d_in[1];
    const float* bq = (const float*)d_in[2];
    const float* Wk = (const float*)d_in[3];
    const float* bk = (const float*)d_in[4];
    const float* Wv = (const float*)d_in[5];
    const float* bv = (const float*)d_in[6];
    const float* pb = (const float*)d_in[7];

    // ws: Qf/Kf/Vf fp32 (12 MB) + Ah/Al bf16 (4 MB) + Wh/Wl bf16 (768 KB)
    const size_t needA = (size_t)3 * 1048576 * 4
                       + ((size_t)2 * 1048576 + (size_t)2 * 196608) * 2;

    if (ws_size >= needA) {
        float* Qf = (float*)d_ws;
        float* Kf = Qf + 1048576;
        float* Vf = Kf + 1048576;
        unsigned short* Ah = (unsigned short*)(Vf + 1048576);
        unsigned short* Al = Ah + 1048576;
        unsigned short* Wh = Al + 1048576;
        unsigned short* Wl = Wh + 196608;

        presplit<<<dim3(608), 256, 0, stream>>>(q, Wq, Wk, Wv, Ah, Al, Wh, Wl);
        qkv_gemm4<<<dim3(128, 2, 3), 256, 0, stream>>>(Ah, Al, Wh, Wl,
                                                       bq, bk, bv, Qf, Kf, Vf);
        aft_stage3<<<dim3(32, 4, 8), 256, 0, stream>>>(Qf, Kf, Vf, pb,
                                                       (float*)d_out);
    } else {
        aft_fused<<<dim3(L_ / TI, B_, E_ / CG), 256, 0, stream>>>(
            q, Wq, bq, Wk, bk, Wv, bv, pb, (float*)d_out);
    }
}